// Round 8
// baseline (857.239 us; speedup 1.0000x reference)
//
#include <hip/hip_runtime.h>

// Output = jacobi(X, Mask1, 100) — the multigrid sweeps in the reference are
// dead code for the returned value (grids[0] is never mutated).
//
// Persistent kernel: 10 phases x 10 fused trapezoid iterations, with a
// hand-rolled sense-reversing grid barrier between phases (cooperative
// launch failed on this harness; this is the same protocol __ockl_grid_sync
// uses: release fence -> device-scope atomic arrive -> spin -> acquire
// fence). Barrier globals self-restore每 call: 10 episodes (9 syncs + 1
// terminal dummy) flip the sense an even number of times and the last
// arriver resets the counter, so g_cnt==0 / g_sense==0 again at exit —
// deterministic across graph replays.
//
// Co-residency (deadlock-freedom): 576 blocks; __launch_bounds__(256,3)
// caps VGPRs at 168 and LDS is 20.7 KB -> >=3 blocks/CU resident even with
// a 64 KB occupancy divisor -> capacity >= 768 > 576, and no block exits
// before the first barrier, so all blocks get dispatched.
//
// Phase body proven in rounds 4-6: 4x4 cells/thread in VGPRs, mask in VGPRs
// for all 100 iterations, LDS = one 20.7 KB set of edge strips, 2 barriers
// per iteration, final iteration of each phase skips edge writes. Tile edges
// compute bounded garbage that never reaches the central 44x44 output window
// (light-cone); the zeroed strip guard ring doubles as zero padding.

#define W 1024
#define H 1024
#define TILE 64
#define TI 10                    // iterations per phase
#define OS (TILE - 2 * TI)       // 44 valid output per tile
#define NB 24                    // ceil(1024/44)
#define NBLK (NB * NB)           // 576
#define NPHASE 10                // NPHASE * TI = 100
#define SR 18                    // strip dim: 16 patches + guard ring

#define S_T 0
#define S_B 1
#define S_L 2
#define S_R 3

__device__ unsigned g_cnt   = 0;
__device__ unsigned g_sense = 0;

__device__ __forceinline__ void grid_barrier(unsigned& local_sense) {
    __syncthreads();                       // all waves' stores drained (vmcnt 0)
    if (threadIdx.x == 0) {
        const unsigned my = local_sense ^ 1u;
        __threadfence();                   // agent release: block's writes -> visible
        unsigned a = __hip_atomic_fetch_add(&g_cnt, 1u, __ATOMIC_RELAXED,
                                            __HIP_MEMORY_SCOPE_AGENT);
        if (a == NBLK - 1) {
            __hip_atomic_store(&g_cnt, 0u, __ATOMIC_RELAXED,
                               __HIP_MEMORY_SCOPE_AGENT);
            __hip_atomic_store(&g_sense, my, __ATOMIC_RELEASE,
                               __HIP_MEMORY_SCOPE_AGENT);
        } else {
            while (__hip_atomic_load(&g_sense, __ATOMIC_ACQUIRE,
                                     __HIP_MEMORY_SCOPE_AGENT) != my)
                __builtin_amdgcn_s_sleep(1);
        }
        __threadfence();                   // agent acquire: invalidate stale caches
    }
    __syncthreads();
    local_sense ^= 1u;
}

__device__ __forceinline__ float2 ld2(const float* __restrict__ p, int gr, int gc) {
    // gc always even, W even -> pair entirely in or out of [0,W); 8B aligned
    if ((unsigned)gr < (unsigned)H && (unsigned)gc < (unsigned)W)
        return *(const float2*)&p[gr * W + gc];
    return make_float2(0.f, 0.f);
}

__device__ __forceinline__ float4 rowstep(const float4 up, const float4 ce,
                                          const float4 dn, const float lf,
                                          const float rt, const float4 m) {
    float4 s, n;
    s.x = (up.x + dn.x) + (lf   + ce.y);
    s.y = (up.y + dn.y) + (ce.x + ce.z);
    s.z = (up.z + dn.z) + (ce.y + ce.w);
    s.w = (up.w + dn.w) + (ce.z + rt);
    n.x = fmaf(m.x, fmaf(0.25f, s.x, -ce.x), ce.x);
    n.y = fmaf(m.y, fmaf(0.25f, s.y, -ce.y), ce.y);
    n.z = fmaf(m.z, fmaf(0.25f, s.z, -ce.z), ce.z);
    n.w = fmaf(m.w, fmaf(0.25f, s.w, -ce.w), ce.w);
    return n;
}

__global__ __launch_bounds__(256, 3) void jacobi_persist(
    const float* __restrict__ X, const float* __restrict__ M,
    float* __restrict__ b0, float* __restrict__ b1)
{
    __shared__ float4 S[4][SR][SR];   // 20.7 KB, single-buffered

    const int tid = threadIdx.x;
    const int pr = tid >> 4, pc = tid & 15;
    const int gx0 = (int)blockIdx.x * OS - TI;
    const int gy0 = (int)blockIdx.y * OS - TI;
    const int gr0 = gy0 + pr * 4;
    const int gc0 = gx0 + pc * 4;               // always even

    unsigned lsense = 0;

    // zero all strips ONCE (guard ring stays 0 for the whole run)
    {
        float4* flat = &S[0][0][0];
        const int tot = 4 * SR * SR;            // 1296
        #pragma unroll
        for (int k = 0; k < 6; ++k) {
            int idx = tid + k * 256;
            if (idx < tot) flat[idx] = make_float4(0.f, 0.f, 0.f, 0.f);
        }
    }

    // mask for my 4x4 patch -> registers ONCE (reused for all 100 iterations)
    float4 m0, m1, m2, m3;
    {
        float4 mm[4];
        #pragma unroll
        for (int i = 0; i < 4; ++i) {
            float2 p2 = ld2(M, gr0 + i, gc0), q2 = ld2(M, gr0 + i, gc0 + 2);
            mm[i] = make_float4(p2.x, p2.y, q2.x, q2.y);
        }
        m0 = mm[0]; m1 = mm[1]; m2 = mm[2]; m3 = mm[3];
    }

    __syncthreads();   // zero-fill visible before any publish

    #pragma unroll 1
    for (int p = 0; p < NPHASE; ++p) {
        if (p) grid_barrier(lsense);   // prev phase's windows visible device-wide

        const float* __restrict__ in = (p == 0) ? X : ((p & 1) ? b0 : b1);
        float* __restrict__       op = (p & 1) ? b1 : b0;   // p9 -> b1 = d_out

        // (re)load my 4x4 cells from the previous phase's output
        float4 c0, c1, c2, c3;
        {
            float4 cc[4];
            #pragma unroll
            for (int i = 0; i < 4; ++i) {
                float2 a = ld2(in, gr0 + i, gc0), b = ld2(in, gr0 + i, gc0 + 2);
                cc[i] = make_float4(a.x, a.y, b.x, b.y);
            }
            c0 = cc[0]; c1 = cc[1]; c2 = cc[2]; c3 = cc[3];
        }

        // publish initial edges
        S[S_T][pr + 1][pc + 1] = c0;
        S[S_B][pr + 1][pc + 1] = c3;
        S[S_L][pr + 1][pc + 1] = make_float4(c0.x, c1.x, c2.x, c3.x);
        S[S_R][pr + 1][pc + 1] = make_float4(c0.w, c1.w, c2.w, c3.w);
        __syncthreads();

        #pragma unroll 1
        for (int it = 0; it < TI - 1; ++it) {
            const float4 th = S[S_B][pr    ][pc + 1];
            const float4 bh = S[S_T][pr + 2][pc + 1];
            const float4 lh = S[S_R][pr + 1][pc    ];
            const float4 rh = S[S_L][pr + 1][pc + 2];
            __syncthreads();                     // all reads done

            const float4 n0 = rowstep(th, c0, c1, lh.x, rh.x, m0);
            const float4 n1 = rowstep(c0, c1, c2, lh.y, rh.y, m1);
            const float4 n2 = rowstep(c1, c2, c3, lh.z, rh.z, m2);
            const float4 n3 = rowstep(c2, c3, bh, lh.w, rh.w, m3);

            S[S_T][pr + 1][pc + 1] = n0;
            S[S_B][pr + 1][pc + 1] = n3;
            S[S_L][pr + 1][pc + 1] = make_float4(n0.x, n1.x, n2.x, n3.x);
            S[S_R][pr + 1][pc + 1] = make_float4(n0.w, n1.w, n2.w, n3.w);

            c0 = n0; c1 = n1; c2 = n2; c3 = n3;
            __syncthreads();                     // writes visible
        }
        // final iteration of the phase: nobody reads these edges -> no LDS
        // writes, no barriers (next S access is after the grid barrier)
        {
            const float4 th = S[S_B][pr    ][pc + 1];
            const float4 bh = S[S_T][pr + 2][pc + 1];
            const float4 lh = S[S_R][pr + 1][pc    ];
            const float4 rh = S[S_L][pr + 1][pc + 2];
            const float4 n0 = rowstep(th, c0, c1, lh.x, rh.x, m0);
            const float4 n1 = rowstep(c0, c1, c2, lh.y, rh.y, m1);
            const float4 n2 = rowstep(c1, c2, c3, lh.z, rh.z, m2);
            const float4 n3 = rowstep(c2, c3, bh, lh.w, rh.w, m3);
            c0 = n0; c1 = n1; c2 = n2; c3 = n3;
        }

        // store central OS x OS window (float2 pairs; pair in/out together)
        #pragma unroll
        for (int i = 0; i < 4; ++i) {
            int lr = pr * 4 + i;
            if (lr < TI || lr >= TILE - TI) continue;
            int gr = gy0 + lr;
            if ((unsigned)gr >= (unsigned)H) continue;
            const float4 ci = (i == 0) ? c0 : (i == 1) ? c1 : (i == 2) ? c2 : c3;
            int lc0 = pc * 4, gc = gx0 + lc0;
            if (lc0 >= TI && lc0 < TILE - TI && (unsigned)gc < (unsigned)W)
                *(float2*)&op[gr * W + gc] = make_float2(ci.x, ci.y);
            int lc2 = lc0 + 2, gc2 = gc + 2;
            if (lc2 >= TI && lc2 < TILE - TI && (unsigned)gc2 < (unsigned)W)
                *(float2*)&op[gr * W + gc2] = make_float2(ci.z, ci.w);
        }
    }

    // terminal dummy episode: makes 10 sense flips per call (even), so
    // g_sense and g_cnt return to 0 -> state identical for the next call.
    grid_barrier(lsense);
}

extern "C" void kernel_launch(void* const* d_in, const int* in_sizes, int n_in,
                              void* d_out, int out_size, void* d_ws, size_t ws_size,
                              hipStream_t stream) {
    const float* X = (const float*)d_in[0];   // (1,1,1024,1024)
    const float* M = (const float*)d_in[1];   // Mask1
    float* out = (float*)d_out;
    float* ws  = (float*)d_ws;                // 4 MB ping buffer

    dim3 grid(NB, NB), block(256);
    // Phase 0 writes ws fully (window union covers domain) before phase 1
    // reads it; odd phases write d_out; phase 9 (odd) leaves result in d_out.
    jacobi_persist<<<grid, block, 0, stream>>>(X, M, ws, out);
}

// Round 9
// 652.853 us; speedup vs baseline: 1.3131x; 1.3131x over previous
//
#include <hip/hip_runtime.h>

// Output = jacobi(X, Mask1, 100) — the multigrid sweeps in the reference are
// dead code for the returned value (grids[0] is never mutated).
//
// Persistent kernel: 10 phases x 10 fused trapezoid iterations with a
// hand-rolled sense-reversing grid barrier. Round-8 lesson: polling with an
// ACQUIRE atomic emitted buffer_inv per poll -> device-wide cache-invalidate
// storm -> 6x slowdown. Fix: RELAXED poll + s_sleep, ONE acquire fence after
// the flip is observed (the __ockl_grid_sync pattern). Release side kept:
// __syncthreads (drains each wave's vmcnt) + lane-0 __threadfence (L2
// writeback), g_sense stored RELEASE so the g_cnt reset is ordered first.
// Barrier state self-restores: 10 sense flips per call (even) + last-arriver
// counter reset -> g_cnt==0/g_sense==0 at exit, deterministic across graph
// replays.
//
// Phase reload exploits persistence: each thread still holds in registers
// exactly what it wrote to the phase output (windows are disjoint, written
// by the same thread) -> only cells OUTSIDE the valid 44x44 window are
// reloaded (per-thread-uniform predicates); interior threads reload nothing.
//
// Co-residency: 576 blocks, 20.7 KB LDS, __launch_bounds__(256,3) -> >= 3
// blocks/CU capacity >= 768 > 576; no block exits before the first barrier.
//
// Body proven in rounds 4-6: 4x4 cells/thread in VGPRs, mask in VGPRs for
// all 100 iterations, LDS = one set of edge strips, 2 barriers/iter, final
// iter of each phase skips edge writes. Tile edges compute bounded garbage
// that never reaches the central window (light-cone); the zeroed strip guard
// ring doubles as zero padding at domain boundaries.

#define W 1024
#define H 1024
#define TILE 64
#define TI 10                    // iterations per phase
#define OS (TILE - 2 * TI)       // 44 valid output per tile
#define NB 24                    // ceil(1024/44)
#define NBLK (NB * NB)           // 576
#define NPHASE 10                // NPHASE * TI = 100
#define SR 18                    // strip dim: 16 patches + guard ring

#define S_T 0
#define S_B 1
#define S_L 2
#define S_R 3

__device__ unsigned g_cnt   = 0;
__device__ unsigned g_sense = 0;

__device__ __forceinline__ void grid_barrier(unsigned& lsense) {
    __syncthreads();                       // all waves' stores drained to L2
    if (threadIdx.x == 0) {
        const unsigned my = lsense ^ 1u;
        __threadfence();                   // release: L2 writeback (agent scope)
        unsigned a = __hip_atomic_fetch_add(&g_cnt, 1u, __ATOMIC_RELAXED,
                                            __HIP_MEMORY_SCOPE_AGENT);
        if (a == NBLK - 1) {
            __hip_atomic_store(&g_cnt, 0u, __ATOMIC_RELAXED,
                               __HIP_MEMORY_SCOPE_AGENT);
            // RELEASE: orders the g_cnt reset before the sense flip
            __hip_atomic_store(&g_sense, my, __ATOMIC_RELEASE,
                               __HIP_MEMORY_SCOPE_AGENT);
        } else {
            // RELAXED poll: atomics read at the coherence point (no L1), and
            // carry no per-poll cache invalidate. Acquire is the fence below.
            while (__hip_atomic_load(&g_sense, __ATOMIC_RELAXED,
                                     __HIP_MEMORY_SCOPE_AGENT) != my)
                __builtin_amdgcn_s_sleep(8);
        }
        __threadfence();                   // acquire: invalidate stale caches once
    }
    __syncthreads();
    lsense ^= 1u;
}

__device__ __forceinline__ float2 ld2(const float* __restrict__ p, int gr, int gc) {
    // gc always even, W even -> pair entirely in or out of [0,W); 8B aligned
    if ((unsigned)gr < (unsigned)H && (unsigned)gc < (unsigned)W)
        return *(const float2*)&p[gr * W + gc];
    return make_float2(0.f, 0.f);
}

__device__ __forceinline__ float4 rowstep(const float4 up, const float4 ce,
                                          const float4 dn, const float lf,
                                          const float rt, const float4 m) {
    float4 s, n;
    s.x = (up.x + dn.x) + (lf   + ce.y);
    s.y = (up.y + dn.y) + (ce.x + ce.z);
    s.z = (up.z + dn.z) + (ce.y + ce.w);
    s.w = (up.w + dn.w) + (ce.z + rt);
    n.x = fmaf(m.x, fmaf(0.25f, s.x, -ce.x), ce.x);
    n.y = fmaf(m.y, fmaf(0.25f, s.y, -ce.y), ce.y);
    n.z = fmaf(m.z, fmaf(0.25f, s.z, -ce.z), ce.z);
    n.w = fmaf(m.w, fmaf(0.25f, s.w, -ce.w), ce.w);
    return n;
}

__global__ __launch_bounds__(256, 3) void jacobi_persist(
    const float* __restrict__ X, const float* __restrict__ M,
    float* __restrict__ b0, float* __restrict__ b1)
{
    __shared__ float4 S[4][SR][SR];   // 20.7 KB, single-buffered

    const int tid = threadIdx.x;
    const int pr = tid >> 4, pc = tid & 15;
    const int gx0 = (int)blockIdx.x * OS - TI;
    const int gy0 = (int)blockIdx.y * OS - TI;
    const int gr0 = gy0 + pr * 4;
    const int gc0 = gx0 + pc * 4;               // always even

    unsigned lsense = 0;

    // zero all strips ONCE (guard ring stays 0 for the whole run)
    {
        float4* flat = &S[0][0][0];
        const int tot = 4 * SR * SR;            // 1296
        #pragma unroll
        for (int k = 0; k < 6; ++k) {
            int idx = tid + k * 256;
            if (idx < tot) flat[idx] = make_float4(0.f, 0.f, 0.f, 0.f);
        }
    }

    // mask for my 4x4 patch -> registers ONCE (reused for all 100 iterations)
    float4 m[4];
    #pragma unroll
    for (int i = 0; i < 4; ++i) {
        float2 p2 = ld2(M, gr0 + i, gc0), q2 = ld2(M, gr0 + i, gc0 + 2);
        m[i] = make_float4(p2.x, p2.y, q2.x, q2.y);
    }

    __syncthreads();   // zero-fill visible before any publish

    // freshness predicates: register value is the phase output (keepable)
    // iff its cell lies in the valid window [TI, TILE-TI) on both axes.
    const bool frL = (pc >= 3) && (pc <= 13);   // cols pc*4, pc*4+1 in [10,53]
    const bool frH = (pc >= 2) && (pc <= 12);   // cols pc*4+2, pc*4+3 in [10,53]

    float4 c[4];

    #pragma unroll 1
    for (int p = 0; p < NPHASE; ++p) {
        if (p) grid_barrier(lsense);   // prev phase's windows visible device-wide

        const float* __restrict__ in = (p == 0) ? X : ((p & 1) ? b0 : b1);
        float* __restrict__       op = (p & 1) ? b1 : b0;   // p9 -> b1 = d_out

        if (p == 0) {
            #pragma unroll
            for (int i = 0; i < 4; ++i) {
                float2 a = ld2(in, gr0 + i, gc0), b = ld2(in, gr0 + i, gc0 + 2);
                c[i] = make_float4(a.x, a.y, b.x, b.y);
            }
        } else {
            // reload only stale cells (outside my valid window); fresh cells
            // already hold the phase output in registers (same thread wrote it)
            #pragma unroll
            for (int i = 0; i < 4; ++i) {
                const int lr = pr * 4 + i;
                const bool rf = (lr >= TI) && (lr < TILE - TI);
                if (!(rf && frL)) {
                    float2 a = ld2(in, gr0 + i, gc0);
                    c[i].x = a.x; c[i].y = a.y;
                }
                if (!(rf && frH)) {
                    float2 b = ld2(in, gr0 + i, gc0 + 2);
                    c[i].z = b.x; c[i].w = b.y;
                }
            }
        }

        // publish initial edges
        S[S_T][pr + 1][pc + 1] = c[0];
        S[S_B][pr + 1][pc + 1] = c[3];
        S[S_L][pr + 1][pc + 1] = make_float4(c[0].x, c[1].x, c[2].x, c[3].x);
        S[S_R][pr + 1][pc + 1] = make_float4(c[0].w, c[1].w, c[2].w, c[3].w);
        __syncthreads();

        #pragma unroll 1
        for (int it = 0; it < TI - 1; ++it) {
            const float4 th = S[S_B][pr    ][pc + 1];
            const float4 bh = S[S_T][pr + 2][pc + 1];
            const float4 lh = S[S_R][pr + 1][pc    ];
            const float4 rh = S[S_L][pr + 1][pc + 2];
            __syncthreads();                     // all reads done

            const float4 n0 = rowstep(th,   c[0], c[1], lh.x, rh.x, m[0]);
            const float4 n1 = rowstep(c[0], c[1], c[2], lh.y, rh.y, m[1]);
            const float4 n2 = rowstep(c[1], c[2], c[3], lh.z, rh.z, m[2]);
            const float4 n3 = rowstep(c[2], c[3], bh,   lh.w, rh.w, m[3]);

            S[S_T][pr + 1][pc + 1] = n0;
            S[S_B][pr + 1][pc + 1] = n3;
            S[S_L][pr + 1][pc + 1] = make_float4(n0.x, n1.x, n2.x, n3.x);
            S[S_R][pr + 1][pc + 1] = make_float4(n0.w, n1.w, n2.w, n3.w);

            c[0] = n0; c[1] = n1; c[2] = n2; c[3] = n3;
            __syncthreads();                     // writes visible
        }
        // final iteration of the phase: nobody reads these edges -> no LDS
        // writes, no barriers (next S access is after the grid barrier)
        {
            const float4 th = S[S_B][pr    ][pc + 1];
            const float4 bh = S[S_T][pr + 2][pc + 1];
            const float4 lh = S[S_R][pr + 1][pc    ];
            const float4 rh = S[S_L][pr + 1][pc + 2];
            const float4 n0 = rowstep(th,   c[0], c[1], lh.x, rh.x, m[0]);
            const float4 n1 = rowstep(c[0], c[1], c[2], lh.y, rh.y, m[1]);
            const float4 n2 = rowstep(c[1], c[2], c[3], lh.z, rh.z, m[2]);
            const float4 n3 = rowstep(c[2], c[3], bh,   lh.w, rh.w, m[3]);
            c[0] = n0; c[1] = n1; c[2] = n2; c[3] = n3;
        }

        // store central OS x OS window (float2 pairs; pair in/out together)
        #pragma unroll
        for (int i = 0; i < 4; ++i) {
            int lr = pr * 4 + i;
            if (lr < TI || lr >= TILE - TI) continue;
            int gr = gy0 + lr;
            if ((unsigned)gr >= (unsigned)H) continue;
            int lc0 = pc * 4, gc = gx0 + lc0;
            if (lc0 >= TI && lc0 < TILE - TI && (unsigned)gc < (unsigned)W)
                *(float2*)&op[gr * W + gc] = make_float2(c[i].x, c[i].y);
            int lc2 = lc0 + 2, gc2 = gc + 2;
            if (lc2 >= TI && lc2 < TILE - TI && (unsigned)gc2 < (unsigned)W)
                *(float2*)&op[gr * W + gc2] = make_float2(c[i].z, c[i].w);
        }
    }

    // terminal dummy episode: 10 sense flips per call (even) -> g_sense and
    // g_cnt return to 0 -> state identical for the next call / graph replay.
    grid_barrier(lsense);
}

extern "C" void kernel_launch(void* const* d_in, const int* in_sizes, int n_in,
                              void* d_out, int out_size, void* d_ws, size_t ws_size,
                              hipStream_t stream) {
    const float* X = (const float*)d_in[0];   // (1,1,1024,1024)
    const float* M = (const float*)d_in[1];   // Mask1
    float* out = (float*)d_out;
    float* ws  = (float*)d_ws;                // 4 MB ping buffer

    dim3 grid(NB, NB), block(256);
    // Phase 0 writes ws fully (window union covers domain) before phase 1
    // reads it; odd phases write d_out; phase 9 (odd) leaves result in d_out.
    jacobi_persist<<<grid, block, 0, stream>>>(X, M, ws, out);
}

// Round 10
// 114.613 us; speedup vs baseline: 7.4794x; 5.6962x over previous
//
#include <hip/hip_runtime.h>

// Output = jacobi(X, Mask1, 100) — the multigrid sweeps in the reference are
// dead code for the returned value (grids[0] is never mutated).
//
// Trapezoidal temporal blocking, register-resident, load-balanced:
// 10 launches x 10 fused iterations. 512-thread blocks, 128x64 tile
// (4x4 cells/thread), valid output window 104x44 -> grid 10x24 = 240 blocks
// = at most ONE block per CU (round-6's 576 blocks @ 2.25/CU made 64 CUs
// run 3 blocks -> 1.33x critical path). Redundancy drops 2.12x -> 1.79x.
// Left halo = 12 (>= TI) so per-thread cols are 16B-aligned -> float4
// global loads/stores. LDS = double-buffered edge strips (78 KB),
// 1 barrier/iter, final iter skips publish+barrier.
// Tile edges compute bounded garbage that never reaches the valid window
// (light-cone); zeroed strip guard ring = zero padding at domain edges.

#define W 1024
#define H 1024
#define TILE_W 128
#define TILE_H 64
#define TI 10                    // fused iterations per launch
#define OS_X 104                 // valid cols per tile: [12, 116)
#define OS_Y 44                  // valid rows per tile: [10, 54)
#define HX 12                    // left col halo (>= TI, keeps 16B alignment)
#define NBX 10                   // 10*104 = 1040 >= 1024
#define NBY 24                   // 24*44  = 1056 >= 1024
#define NLAUNCH 10               // NLAUNCH * TI = 100

// strip grids: 16 patch-rows x 32 patch-cols + guard ring
#define SRr 18
#define SRc 34
#define S_T 0
#define S_B 1
#define S_L 2
#define S_R 3

__device__ __forceinline__ float4 ld4(const float* __restrict__ p, int gr, int gc) {
    // gc is a multiple of 4 and W%4==0 -> the quad is entirely in or out
    if ((unsigned)gr < (unsigned)H && (unsigned)gc < (unsigned)W)
        return *(const float4*)&p[gr * W + gc];
    return make_float4(0.f, 0.f, 0.f, 0.f);
}

__device__ __forceinline__ float4 rowstep(const float4 up, const float4 ce,
                                          const float4 dn, const float lf,
                                          const float rt, const float4 m) {
    float4 s, n;
    s.x = (up.x + dn.x) + (lf   + ce.y);
    s.y = (up.y + dn.y) + (ce.x + ce.z);
    s.z = (up.z + dn.z) + (ce.y + ce.w);
    s.w = (up.w + dn.w) + (ce.z + rt);
    n.x = fmaf(m.x, fmaf(0.25f, s.x, -ce.x), ce.x);
    n.y = fmaf(m.y, fmaf(0.25f, s.y, -ce.y), ce.y);
    n.z = fmaf(m.z, fmaf(0.25f, s.z, -ce.z), ce.z);
    n.w = fmaf(m.w, fmaf(0.25f, s.w, -ce.w), ce.w);
    return n;
}

__global__ __launch_bounds__(512, 1) void jacobi_trap(
    const float* __restrict__ xin, const float* __restrict__ mask,
    float* __restrict__ xout)
{
    __shared__ float4 S[2][4][SRr][SRc];   // 78.3 KB

    const int tid = threadIdx.x;
    const int pr = tid >> 5;               // 0..15
    const int pc = tid & 31;               // 0..31
    const int gx0 = (int)blockIdx.x * OS_X - HX;
    const int gy0 = (int)blockIdx.y * OS_Y - TI;
    const int gr0 = gy0 + pr * 4;
    const int gc0 = gx0 + pc * 4;          // multiple of 4

    // zero both strip buffers (guard ring must be 0; interior overwritten)
    {
        float4* flat = &S[0][0][0][0];
        const int tot = 2 * 4 * SRr * SRc; // 4896
        #pragma unroll
        for (int k = 0; k < 10; ++k) {
            int idx = tid + k * 512;
            if (idx < tot) flat[idx] = make_float4(0.f, 0.f, 0.f, 0.f);
        }
    }

    // cells + mask -> registers (mask reused for all TI iterations)
    float4 c[4], m[4];
    #pragma unroll
    for (int i = 0; i < 4; ++i) {
        c[i] = ld4(xin,  gr0 + i, gc0);
        m[i] = ld4(mask, gr0 + i, gc0);
    }

    __syncthreads();   // zero-fill complete before edge publish

    // publish initial edges into buffer 0
    S[0][S_T][pr + 1][pc + 1] = c[0];
    S[0][S_B][pr + 1][pc + 1] = c[3];
    S[0][S_L][pr + 1][pc + 1] = make_float4(c[0].x, c[1].x, c[2].x, c[3].x);
    S[0][S_R][pr + 1][pc + 1] = make_float4(c[0].w, c[1].w, c[2].w, c[3].w);
    __syncthreads();

    #pragma unroll 1
    for (int it = 0; it < TI; ++it) {
        const int rb = it & 1;
        const float4 th = S[rb][S_B][pr    ][pc + 1];
        const float4 bh = S[rb][S_T][pr + 2][pc + 1];
        const float4 lh = S[rb][S_R][pr + 1][pc    ];
        const float4 rh = S[rb][S_L][pr + 1][pc + 2];

        const float4 n0 = rowstep(th,   c[0], c[1], lh.x, rh.x, m[0]);
        const float4 n1 = rowstep(c[0], c[1], c[2], lh.y, rh.y, m[1]);
        const float4 n2 = rowstep(c[1], c[2], c[3], lh.z, rh.z, m[2]);
        const float4 n3 = rowstep(c[2], c[3], bh,   lh.w, rh.w, m[3]);
        c[0] = n0; c[1] = n1; c[2] = n2; c[3] = n3;

        if (it < TI - 1) {   // last iter: nobody reads these edges
            const int wb = rb ^ 1;
            S[wb][S_T][pr + 1][pc + 1] = n0;
            S[wb][S_B][pr + 1][pc + 1] = n3;
            S[wb][S_L][pr + 1][pc + 1] = make_float4(n0.x, n1.x, n2.x, n3.x);
            S[wb][S_R][pr + 1][pc + 1] = make_float4(n0.w, n1.w, n2.w, n3.w);
            __syncthreads();
        }
    }

    // store valid window: rows [TI, TILE_H-TI), cols [HX, HX+OS_X)
    const int lc = pc * 4;
    if (lc >= HX && lc < HX + OS_X && (unsigned)gc0 < (unsigned)W) {
        #pragma unroll
        for (int i = 0; i < 4; ++i) {
            int lr = pr * 4 + i;
            if (lr < TI || lr >= TILE_H - TI) continue;
            int gr = gy0 + lr;
            if ((unsigned)gr >= (unsigned)H) continue;
            *(float4*)&xout[gr * W + gc0] = c[i];
        }
    }
}

extern "C" void kernel_launch(void* const* d_in, const int* in_sizes, int n_in,
                              void* d_out, int out_size, void* d_ws, size_t ws_size,
                              hipStream_t stream) {
    const float* X = (const float*)d_in[0];   // (1,1,1024,1024)
    const float* M = (const float*)d_in[1];   // Mask1
    float* out = (float*)d_out;
    float* ws  = (float*)d_ws;                // 4 MB ping buffer

    dim3 grid(NBX, NBY), block(512);
    // l=0: X->ws; alternate; l=9 (odd) -> out. Valid-window union covers
    // the full domain, so ws/out are fully written before any read.
    const float* src = X;
    for (int l = 0; l < NLAUNCH; ++l) {
        float* dst = (l & 1) ? out : ws;
        jacobi_trap<<<grid, block, 0, stream>>>(src, M, dst);
        src = dst;
    }
}